// Round 17
// baseline (93.755 us; speedup 1.0000x reference)
//
#include <hip/hip_runtime.h>
#include <hip/hip_bf16.h>

typedef __bf16 bf16x8 __attribute__((ext_vector_type(8)));
typedef float  f32x4  __attribute__((ext_vector_type(4)));

#define SEQ   1024
#define BATCH 8
#define DIMM  512
#define HEADS 8
#define DHEAD 64
#define TRIPLE 1536
#define MROWS (BATCH*SEQ)   // 8192

#define GLOAD_LDS16(g, l) __builtin_amdgcn_global_load_lds( \
    (const __attribute__((address_space(1))) void*)(const void*)(g), \
    (__attribute__((address_space(3))) void*)(void*)(l), 16, 0, 0)

// ---------------- merged |w| partial sums ----------------
__global__ __launch_bounds__(256) void absum_all(const float* __restrict__ w1,
                                                 const float* __restrict__ w2,
                                                 float* __restrict__ part) {
    const int bid = blockIdx.x, tid = threadIdx.x;
    float s = 0.f;
    if (bid < 256) {
        const float4* p = (const float4*)w1;
        for (int i = bid * 256 + tid; i < 196608; i += 65536) {
            float4 v = p[i];
            s += fabsf(v.x) + fabsf(v.y) + fabsf(v.z) + fabsf(v.w);
        }
    } else {
        const float4* p = (const float4*)w2;
        for (int i = (bid - 256) * 256 + tid; i < 65536; i += 16384) {
            float4 v = p[i];
            s += fabsf(v.x) + fabsf(v.y) + fabsf(v.z) + fabsf(v.w);
        }
    }
    for (int o = 32; o; o >>= 1) s += __shfl_down(s, o);
    __shared__ float red[4];
    if (!(tid & 63)) red[tid >> 6] = s;
    __syncthreads();
    if (tid == 0) part[bid] = red[0] + red[1] + red[2] + red[3];
}

// ---------------- ternary quantize -> bf16 (finalize fused) ----------------
__global__ __launch_bounds__(256) void quant_all(const float* __restrict__ w1,
                                                 const float* __restrict__ w2,
                                                 const float* __restrict__ part,
                                                 __bf16* __restrict__ o1,
                                                 __bf16* __restrict__ o2) {
    const int bid = blockIdx.x, tid = threadIdx.x;
    float acc = 0.f;
    if (bid < 768) acc = part[tid];
    else if (tid < 64) acc = part[256 + tid];
    for (int o = 32; o; o >>= 1) acc += __shfl_down(acc, o);
    __shared__ float red[4];
    if (!(tid & 63)) red[tid >> 6] = acc;
    __syncthreads();
    const float tot = red[0] + red[1] + red[2] + red[3];
    const float s = (bid < 768) ? tot / 786432.0f : tot / 262144.0f;
    const float inv = 1.f / (s + 1e-6f);

    const float* w; __bf16* o; int idx;
    if (bid < 768) { w = w1; o = o1; idx = (bid * 256 + tid) * 4; }
    else           { w = w2; o = o2; idx = ((bid - 768) * 256 + tid) * 4; }
    float4 v = *reinterpret_cast<const float4*>(w + idx);
    o[idx + 0] = (__bf16)(rintf(fminf(1.f, fmaxf(-1.f, v.x * inv))) * s);
    o[idx + 1] = (__bf16)(rintf(fminf(1.f, fmaxf(-1.f, v.y * inv))) * s);
    o[idx + 2] = (__bf16)(rintf(fminf(1.f, fmaxf(-1.f, v.z * inv))) * s);
    o[idx + 3] = (__bf16)(rintf(fminf(1.f, fmaxf(-1.f, v.w * inv))) * s);
}

// ---------------- wave-per-row layernorm (row = 512), output bf16 ----------------
template<typename TIN>
__global__ __launch_bounds__(256) void ln_fast(const TIN* __restrict__ x,
                                               const float* __restrict__ g,
                                               const float* __restrict__ bta,
                                               __bf16* __restrict__ y) {
    const int row = blockIdx.x * 4 + (threadIdx.x >> 6);
    const int lane = threadIdx.x & 63;
    float v[8];
    if constexpr (sizeof(TIN) == 4) {
        const float4* xr = (const float4*)((const float*)x + (size_t)row * DIMM + lane * 8);
        float4 a = xr[0], bq = xr[1];
        v[0] = a.x; v[1] = a.y; v[2] = a.z; v[3] = a.w;
        v[4] = bq.x; v[5] = bq.y; v[6] = bq.z; v[7] = bq.w;
    } else {
        bf16x8 a = *reinterpret_cast<const bf16x8*>((const __bf16*)x + (size_t)row * DIMM + lane * 8);
#pragma unroll
        for (int e = 0; e < 8; ++e) v[e] = (float)a[e];
    }
    float s = 0.f, sq = 0.f;
#pragma unroll
    for (int e = 0; e < 8; ++e) { s += v[e]; sq += v[e] * v[e]; }
    for (int o = 32; o; o >>= 1) { s += __shfl_xor(s, o); sq += __shfl_xor(sq, o); }
    const float mu = s * (1.f / DIMM);
    const float invs = rsqrtf(sq * (1.f / DIMM) - mu * mu + 1e-5f);
    const float4* gp = (const float4*)(g + lane * 8);
    const float4* bp = (const float4*)(bta + lane * 8);
    float4 g0 = gp[0], g1 = gp[1], b0 = bp[0], b1 = bp[1];
    float o_[8] = {
        (v[0] - mu) * invs * g0.x + b0.x, (v[1] - mu) * invs * g0.y + b0.y,
        (v[2] - mu) * invs * g0.z + b0.z, (v[3] - mu) * invs * g0.w + b0.w,
        (v[4] - mu) * invs * g1.x + b1.x, (v[5] - mu) * invs * g1.y + b1.y,
        (v[6] - mu) * invs * g1.z + b1.z, (v[7] - mu) * invs * g1.w + b1.w };
    uint4 st;
    asm("v_cvt_pk_bf16_f32 %0, %1, %2" : "=v"(st.x) : "v"(o_[0]), "v"(o_[1]));
    asm("v_cvt_pk_bf16_f32 %0, %1, %2" : "=v"(st.y) : "v"(o_[2]), "v"(o_[3]));
    asm("v_cvt_pk_bf16_f32 %0, %1, %2" : "=v"(st.z) : "v"(o_[4]), "v"(o_[5]));
    asm("v_cvt_pk_bf16_f32 %0, %1, %2" : "=v"(st.w) : "v"(o_[6]), "v"(o_[7]));
    *reinterpret_cast<uint4*>(y + (size_t)row * DIMM + lane * 8) = st;
}

// ---------------- LDS-staged MFMA GEMM (round-6 exact) ----------------
template<int NCOLS, bool BIAS, bool OUT_F32>
__global__ __launch_bounds__(256) void gemm_lds(const __bf16* __restrict__ A,
                                                const __bf16* __restrict__ Wt,
                                                const float* __restrict__ bias,
                                                __bf16* __restrict__ outb,
                                                float* __restrict__ outf) {
    const int K = DIMM;
    __shared__ __align__(16) __bf16 As[2][4096];
    __shared__ __align__(16) __bf16 Bs[2][4096];

    const int tid = threadIdx.x;
    const int w = tid >> 6, lane = tid & 63;
    const int m = lane & 15, g = lane >> 4;
    const int mi = w >> 1, ni = w & 1;

    const int trow = tid >> 2;
    const int tc = tid & 3;
    const int sc = (tc ^ ((trow >> 1) & 3)) * 8;
    const __bf16* a0 = A  + (size_t)(blockIdx.x * 128 + trow) * K + sc;
    const __bf16* a1 = a0 + (size_t)64 * K;
    const __bf16* b0 = Wt + (size_t)(blockIdx.y * 128 + trow) * K + sc;
    const __bf16* b1 = b0 + (size_t)64 * K;

    f32x4 acc[4][4] = {};

    GLOAD_LDS16(a0, (char*)As[0] + tid * 16);
    GLOAD_LDS16(a1, (char*)As[0] + 4096 + tid * 16);
    GLOAD_LDS16(b0, (char*)Bs[0] + tid * 16);
    GLOAD_LDS16(b1, (char*)Bs[0] + 4096 + tid * 16);

    int cur = 0;
    for (int k0 = 0; k0 < K; k0 += 32) {
        __syncthreads();
        if (k0 + 32 < K) {
            GLOAD_LDS16(a0 + k0 + 32, (char*)As[cur ^ 1] + tid * 16);
            GLOAD_LDS16(a1 + k0 + 32, (char*)As[cur ^ 1] + 4096 + tid * 16);
            GLOAD_LDS16(b0 + k0 + 32, (char*)Bs[cur ^ 1] + tid * 16);
            GLOAD_LDS16(b1 + k0 + 32, (char*)Bs[cur ^ 1] + 4096 + tid * 16);
        }

        const char* Ab = (const char*)As[cur];
        const char* Bb = (const char*)Bs[cur];
        bf16x8 af[4], bfr[4];
#pragma unroll
        for (int i = 0; i < 4; ++i) {
            const int ra = mi * 64 + i * 16 + m;
            af[i] = *reinterpret_cast<const bf16x8*>(Ab + ra * 64 + ((g ^ ((ra >> 1) & 3)) << 4));
        }
#pragma unroll
        for (int j = 0; j < 4; ++j) {
            const int rb = ni * 64 + j * 16 + m;
            bfr[j] = *reinterpret_cast<const bf16x8*>(Bb + rb * 64 + ((g ^ ((rb >> 1) & 3)) << 4));
        }
#pragma unroll
        for (int i = 0; i < 4; ++i)
#pragma unroll
            for (int j = 0; j < 4; ++j)
                acc[i][j] = __builtin_amdgcn_mfma_f32_16x16x32_bf16(af[i], bfr[j], acc[i][j], 0, 0, 0);
        cur ^= 1;
    }

    const int orow0 = blockIdx.x * 128 + mi * 64 + g * 4;
    const int ocol0 = blockIdx.y * 128 + ni * 64;
#pragma unroll
    for (int i = 0; i < 4; ++i)
#pragma unroll
        for (int j = 0; j < 4; ++j)
#pragma unroll
            for (int r = 0; r < 4; ++r) {
                int row = orow0 + i * 16 + r;
                int col = ocol0 + j * 16 + m;
                float v = acc[i][j][r];
                if (BIAS) v += bias[col];
                if (OUT_F32) outf[(size_t)row * NCOLS + col] = v;
                else         outb[(size_t)row * NCOLS + col] = (__bf16)v;
            }
}

// ---------------- V transpose: qkv V-part [token][d] -> VT [bh][d][token] ----------------
// (verified r14/r15/r16) grid (64 bh, 16 nt) so lin%8 == h.
__global__ __launch_bounds__(256) void transpose_v(const __bf16* __restrict__ qkv,
                                                   __bf16* __restrict__ vtg) {
    __shared__ __align__(16) __bf16 Vl[4096];   // [64 tok][64 d], chunk c at c^(tok&7)
    const int bh = blockIdx.x, nt = blockIdx.y;
    const int b = bh >> 3, h = bh & 7;
    const int tid = threadIdx.x;
    const int r = tid >> 3, c = tid & 7;
    const __bf16* src = qkv + (size_t)(b * SEQ + nt * 64 + r) * TRIPLE + 2 * DIMM + h * 64 + c * 8;
    uint4 v0 = *reinterpret_cast<const uint4*>(src);
    uint4 v1 = *reinterpret_cast<const uint4*>(src + (size_t)32 * TRIPLE);
    char* lp = (char*)Vl;
    *reinterpret_cast<uint4*>(lp + r * 128 + ((c ^ (r & 7)) << 4)) = v0;
    *reinterpret_cast<uint4*>(lp + (r + 32) * 128 + ((c ^ (r & 7)) << 4)) = v1;
    __syncthreads();
    const int d = tid >> 2, qtr = tid & 3;
    const int cd = d >> 3, dby = (d & 7) * 2;
    unsigned un[8];
#pragma unroll
    for (int s2 = 0; s2 < 8; ++s2) {
        const int tok0 = qtr * 16 + s2 * 2, tok1 = tok0 + 1;
        unsigned lo = *reinterpret_cast<const unsigned short*>(lp + tok0 * 128 + ((cd ^ (tok0 & 7)) << 4) + dby);
        unsigned hi = *reinterpret_cast<const unsigned short*>(lp + tok1 * 128 + ((cd ^ (tok1 & 7)) << 4) + dby);
        un[s2] = lo | (hi << 16);
    }
    __bf16* dst = vtg + (size_t)(bh * 64 + d) * SEQ + nt * 64 + qtr * 16;
    *reinterpret_cast<uint4*>(dst)     = make_uint4(un[0], un[1], un[2], un[3]);
    *reinterpret_cast<uint4*>(dst + 8) = make_uint4(un[4], un[5], un[6], un[7]);
}

// ---------------- MFMA flash attention: DMA-staged dbuf + 32 q-rows/wave ----------------
// grid (64 bh, 8 qt); 256 threads = 4 waves, 32 q-rows/wave (two r6-verified halves).
// Staging = r16-verified DMA dbuf (q-count-independent, byte-identical); compute body
// = r6-verified two-half softmax/P/PV with r16's V-read swizzle; grid = r12-verified
// bh-major XCD mapping. K/V LDS reads amortized over 2x output rows.
__global__ __launch_bounds__(256, 2) void attn_mfma(const __bf16* __restrict__ qkv,
                                                    const __bf16* __restrict__ vtg,
                                                    __bf16* __restrict__ out) {
    const int bh = blockIdx.x, qt = blockIdx.y;
    const int b = bh >> 3, h = bh & 7;
    const int tid = threadIdx.x;
    const int w = tid >> 6, lane = tid & 63;
    const int g = lane >> 4, m = lane & 15;

    __shared__ __align__(16) __bf16 Kb[2][4096];   // [64 key][64 d], chunk c of row r at c^(r&7)
    __shared__ __align__(16) __bf16 Vb[2][4096];   // [64 d][64 key], same layout
    __shared__ __align__(16) __bf16 Pl[4][2048];   // per-wave [32 q][64 key]

    // Q fragments: qf[hf][kc] = Q[q = hf*16+m][d = kc*32 + g*8 + j] * 0.125 (exact in bf16)
    bf16x8 qf[2][2];
    {
        const __bf16* qp = qkv + (size_t)(b * SEQ + qt * 128 + w * 32 + m) * TRIPLE + h * 64 + g * 8;
#pragma unroll
        for (int hf = 0; hf < 2; ++hf) {
            qf[hf][0] = *reinterpret_cast<const bf16x8*>(qp + (size_t)hf * 16 * TRIPLE);
            qf[hf][1] = *reinterpret_cast<const bf16x8*>(qp + (size_t)hf * 16 * TRIPLE + 32);
#pragma unroll
            for (int e = 0; e < 8; ++e) {
                qf[hf][0][e] = (__bf16)((float)qf[hf][0][e] * 0.125f);
                qf[hf][1][e] = (__bf16)((float)qf[hf][1][e] * 0.125f);
            }
        }
    }

    // staging (r16 verbatim): thread -> LDS (row sr, pos sp), logical chunk scn = sp^(sr&7)
    const int sr = tid >> 3;            // 0..31
    const int sp = tid & 7;             // 0..7
    const int scn = sp ^ (sr & 7);
    const __bf16* ksrc = qkv + (size_t)(b * SEQ + sr) * TRIPLE + DIMM + h * 64 + scn * 8;
    const __bf16* vsrc = vtg + (size_t)(bh * 64 + sr) * SEQ + scn * 8;
    const size_t kstep = (size_t)64 * TRIPLE;

    auto stage = [&](int bb, int t) {
        GLOAD_LDS16(ksrc + (size_t)t * kstep,                       (char*)Kb[bb] + tid * 16);
        GLOAD_LDS16(ksrc + (size_t)t * kstep + (size_t)32 * TRIPLE, (char*)Kb[bb] + 4096 + tid * 16);
        GLOAD_LDS16(vsrc + t * 64,                                  (char*)Vb[bb] + tid * 16);
        GLOAD_LDS16(vsrc + t * 64 + (size_t)32 * SEQ,               (char*)Vb[bb] + 4096 + tid * 16);
    };

    f32x4 oa[2][4] = {};
    float mrun[2] = {-1e30f, -1e30f}, lrun[2] = {0.f, 0.f};
    char* pw = (char*)Pl[w] + m * 128;
    const int psw = (m & 7) << 4;

    stage(0, 0);
    int cur = 0;
    for (int t = 0; t < 16; ++t) {
        __syncthreads();                 // drains buf[cur] DMA; buf[cur^1] fully consumed
        if (t < 15) stage(cur ^ 1, t + 1);

        const char* kb = (const char*)Kb[cur];
        const char* vb = (const char*)Vb[cur];

        // ---- S^T = K @ Q^T (K-frags shared by both halves) ----
        f32x4 sa[2][4];
#pragma unroll
        for (int hf = 0; hf < 2; ++hf)
#pragma unroll
            for (int i = 0; i < 4; ++i) sa[hf][i] = (f32x4){0.f, 0.f, 0.f, 0.f};
#pragma unroll
        for (int kc = 0; kc < 2; ++kc) {
            const int cp = ((kc * 4 + g) ^ (m & 7)) << 4;
#pragma unroll
            for (int i = 0; i < 4; ++i) {
                bf16x8 kf = *reinterpret_cast<const bf16x8*>(kb + (i * 16 + m) * 128 + cp);
                sa[0][i] = __builtin_amdgcn_mfma_f32_16x16x32_bf16(kf, qf[0][kc], sa[0][i], 0, 0, 0);
                sa[1][i] = __builtin_amdgcn_mfma_f32_16x16x32_bf16(kf, qf[1][kc], sa[1][i], 0, 0, 0);
            }
        }

        // ---- online softmax per half + P pack/store (r6 verbatim) ----
#pragma unroll
        for (int hf = 0; hf < 2; ++hf) {
            float mx = -1e30f;
#pragma unroll
            for (int i = 0; i < 4; ++i)
#pragma unroll
                for (int r = 0; r < 4; ++r) mx = fmaxf(mx, sa[hf][i][r]);
            mx = fmaxf(mx, __shfl_xor(mx, 16));
            mx = fmaxf(mx, __shfl_xor(mx, 32));
            const float mnew = fmaxf(mrun[hf], mx);
            float p[4][4];
            float ps = 0.f;
#pragma unroll
            for (int i = 0; i < 4; ++i)
#pragma unroll
                for (int r = 0; r < 4; ++r) { p[i][r] = __expf(sa[hf][i][r] - mnew); ps += p[i][r]; }
            ps += __shfl_xor(ps, 16);
            ps += __shfl_xor(ps, 32);
            const float al = __expf(mrun[hf] - mnew);
            mrun[hf] = mnew;
            lrun[hf] = lrun[hf] * al + ps;
#pragma unroll
            for (int i = 0; i < 4; ++i)
#pragma unroll
                for (int r = 0; r < 4; ++r) oa[hf][i][r] *= al;
#pragma unroll
            for (int i = 0; i < 4; ++i) {
                uint2 pk;
                asm("v_cvt_pk_bf16_f32 %0, %1, %2" : "=v"(pk.x) : "v"(p[i][0]), "v"(p[i][1]));
                asm("v_cvt_pk_bf16_f32 %0, %1, %2" : "=v"(pk.y) : "v"(p[i][2]), "v"(p[i][3]));
                *reinterpret_cast<uint2*>(pw + hf * 16 * 128 + ((i * 32 + g * 8) ^ psw)) = pk;
            }
        }

        // ---- P fragments (per-wave LDS, same-wave ordering) ----
        bf16x8 pf[2][2];
#pragma unroll
        for (int hf = 0; hf < 2; ++hf)
#pragma unroll
            for (int kc = 0; kc < 2; ++kc)
                pf[hf][kc] = *reinterpret_cast<const bf16x8*>(
                    pw + hf * 16 * 128 + ((kc * 64 + g * 16) ^ psw));

        // ---- O^T += V^T @ P^T (V-frags shared by both halves; r16 read swizzle) ----
#pragma unroll
        for (int kc = 0; kc < 2; ++kc) {
            const int cp = ((kc * 4 + g) ^ (m & 7)) << 4;
#pragma unroll
            for (int i = 0; i < 4; ++i) {
                bf16x8 vf = *reinterpret_cast<const bf16x8*>(vb + (i * 16 + m) * 128 + cp);
                oa[0][i] = __builtin_amdgcn_mfma_f32_16x16x32_bf16(vf, pf[0][kc], oa[0][i], 0, 0, 0);
                oa[1][i] = __builtin_amdgcn_mfma_f32_16x16x32_bf16(vf, pf[1][kc], oa[1][i], 0, 0, 0);
            }
        }

        cur ^= 1;
    }

    // ---- epilogue (r6 verbatim) ----
#pragma unroll
    for (int hf = 0; hf < 2; ++hf) {
        const float inv = 1.0f / lrun[hf];
        unsigned int* orow = (unsigned int*)(out +
            (size_t)(b * SEQ + qt * 128 + w * 32 + hf * 16 + m) * DIMM + h * 64);
#pragma unroll
        for (int i = 0; i < 4; ++i)
#pragma unroll
            for (int rp = 0; rp < 2; ++rp) {
                float o0 = oa[hf][i][2 * rp] * inv, o1 = oa[hf][i][2 * rp + 1] * inv;
                unsigned int pk;
                asm("v_cvt_pk_bf16_f32 %0, %1, %2" : "=v"(pk) : "v"(o0), "v"(o1));
                orow[i * 8 + g * 2 + rp] = pk;
            }
    }
}

// ---------------- launch ----------------
extern "C" void kernel_launch(void* const* d_in, const int* in_sizes, int n_in,
                              void* d_out, int out_size, void* d_ws, size_t ws_size,
                              hipStream_t stream) {
    const float* x     = (const float*)d_in[0];
    const float* g1    = (const float*)d_in[1];
    const float* b1    = (const float*)d_in[2];
    const float* W_qkv = (const float*)d_in[3];
    const float* g2    = (const float*)d_in[4];
    const float* b2    = (const float*)d_in[5];
    const float* W_out = (const float*)d_in[6];
    const float* b_out = (const float*)d_in[7];
    float* out = (float*)d_out;

    char* ws = (char*)d_ws;
    float* part   = (float*)(ws);                                // 320 floats
    __bf16* Wq1 = (__bf16*)(ws + 4096);                          // [1536,512]
    __bf16* Wq2 = (__bf16*)(ws + 4096 + 1572864);                // [512,512]
    __bf16* Xln = (__bf16*)(ws + 4096 + 1572864 + 524288);       // [8192,512] (reused for LN2 out)
    __bf16* QKV = (__bf16*)(ws + 4096 + 1572864 + 524288 + 8388608);            // [8192,1536]
    __bf16* AO  = (__bf16*)(ws + 4096 + 1572864 + 524288 + 8388608 + 25165824); // [8192,512]
    // VT aliases Xln (both 8 MB): Xln dead after gemm1; transpose_v + attn both
    // complete before ln_fast rewrites Xln (stream order). Peak ws = proven 44 MB.
    __bf16* VT  = Xln;                                           // [64 bh][64 d][1024 tok]

    absum_all<<<320, 256, 0, stream>>>(W_qkv, W_out, part);
    quant_all<<<1024, 256, 0, stream>>>(W_qkv, W_out, part, Wq1, Wq2);
    ln_fast<float><<<MROWS / 4, 256, 0, stream>>>(x, g1, b1, Xln);
    gemm_lds<TRIPLE, false, false><<<dim3(64, 12), 256, 0, stream>>>(Xln, Wq1, nullptr, QKV, nullptr);
    transpose_v<<<dim3(64, 16), 256, 0, stream>>>(QKV, VT);
    attn_mfma<<<dim3(64, 8), 256, 0, stream>>>(QKV, VT, AO);
    ln_fast<__bf16><<<MROWS / 4, 256, 0, stream>>>(AO, g2, b2, Xln);
    gemm_lds<DIMM, true, true><<<dim3(64, 4), 256, 0, stream>>>(Xln, Wq2, b_out, nullptr, out);
}

// Round 18
// 93.061 us; speedup vs baseline: 1.0075x; 1.0075x over previous
//
#include <hip/hip_runtime.h>
#include <hip/hip_bf16.h>

typedef __bf16 bf16x8 __attribute__((ext_vector_type(8)));
typedef float  f32x4  __attribute__((ext_vector_type(4)));

#define SEQ   1024
#define BATCH 8
#define DIMM  512
#define HEADS 8
#define DHEAD 64
#define TRIPLE 1536
#define MROWS (BATCH*SEQ)   // 8192

#define GLOAD_LDS16(g, l) __builtin_amdgcn_global_load_lds( \
    (const __attribute__((address_space(1))) void*)(const void*)(g), \
    (__attribute__((address_space(3))) void*)(void*)(l), 16, 0, 0)

// ---------------- merged |w| partial sums ----------------
__global__ __launch_bounds__(256) void absum_all(const float* __restrict__ w1,
                                                 const float* __restrict__ w2,
                                                 float* __restrict__ part) {
    const int bid = blockIdx.x, tid = threadIdx.x;
    float s = 0.f;
    if (bid < 256) {
        const float4* p = (const float4*)w1;
        for (int i = bid * 256 + tid; i < 196608; i += 65536) {
            float4 v = p[i];
            s += fabsf(v.x) + fabsf(v.y) + fabsf(v.z) + fabsf(v.w);
        }
    } else {
        const float4* p = (const float4*)w2;
        for (int i = (bid - 256) * 256 + tid; i < 65536; i += 16384) {
            float4 v = p[i];
            s += fabsf(v.x) + fabsf(v.y) + fabsf(v.z) + fabsf(v.w);
        }
    }
    for (int o = 32; o; o >>= 1) s += __shfl_down(s, o);
    __shared__ float red[4];
    if (!(tid & 63)) red[tid >> 6] = s;
    __syncthreads();
    if (tid == 0) part[bid] = red[0] + red[1] + red[2] + red[3];
}

// ---------------- fused: ternary quantize (blocks 0..1023) || LN1 (blocks 1024..3071) ----------------
__global__ __launch_bounds__(256) void quant_ln(const float* __restrict__ w1,
                                                const float* __restrict__ w2,
                                                const float* __restrict__ part,
                                                const float* __restrict__ x,
                                                const float* __restrict__ g1,
                                                const float* __restrict__ b1,
                                                __bf16* __restrict__ o1,
                                                __bf16* __restrict__ o2,
                                                __bf16* __restrict__ y) {
    const int bid = blockIdx.x, tid = threadIdx.x;
    if (bid < 1024) {
        // ---- quant path (r13-verified body) ----
        float acc = 0.f;
        if (bid < 768) acc = part[tid];
        else if (tid < 64) acc = part[256 + tid];
        for (int o = 32; o; o >>= 1) acc += __shfl_down(acc, o);
        __shared__ float red[4];
        if (!(tid & 63)) red[tid >> 6] = acc;
        __syncthreads();
        const float tot = red[0] + red[1] + red[2] + red[3];
        const float s = (bid < 768) ? tot / 786432.0f : tot / 262144.0f;
        const float inv = 1.f / (s + 1e-6f);
        const float* w; __bf16* o; int idx;
        if (bid < 768) { w = w1; o = o1; idx = (bid * 256 + tid) * 4; }
        else           { w = w2; o = o2; idx = ((bid - 768) * 256 + tid) * 4; }
        float4 v = *reinterpret_cast<const float4*>(w + idx);
        o[idx + 0] = (__bf16)(rintf(fminf(1.f, fmaxf(-1.f, v.x * inv))) * s);
        o[idx + 1] = (__bf16)(rintf(fminf(1.f, fmaxf(-1.f, v.y * inv))) * s);
        o[idx + 2] = (__bf16)(rintf(fminf(1.f, fmaxf(-1.f, v.z * inv))) * s);
        o[idx + 3] = (__bf16)(rintf(fminf(1.f, fmaxf(-1.f, v.w * inv))) * s);
    } else {
        // ---- LN1 path (ln_fast<float> verified body) ----
        const int row = (bid - 1024) * 4 + (tid >> 6);
        const int lane = tid & 63;
        const float4* xr = (const float4*)(x + (size_t)row * DIMM + lane * 8);
        float4 a = xr[0], bq = xr[1];
        float v[8] = {a.x, a.y, a.z, a.w, bq.x, bq.y, bq.z, bq.w};
        float s = 0.f, sq = 0.f;
#pragma unroll
        for (int e = 0; e < 8; ++e) { s += v[e]; sq += v[e] * v[e]; }
        for (int o = 32; o; o >>= 1) { s += __shfl_xor(s, o); sq += __shfl_xor(sq, o); }
        const float mu = s * (1.f / DIMM);
        const float invs = rsqrtf(sq * (1.f / DIMM) - mu * mu + 1e-5f);
        const float4* gp = (const float4*)(g1 + lane * 8);
        const float4* bp = (const float4*)(b1 + lane * 8);
        float4 g0 = gp[0], g1v = gp[1], b0 = bp[0], b1v = bp[1];
        float o_[8] = {
            (v[0] - mu) * invs * g0.x + b0.x, (v[1] - mu) * invs * g0.y + b0.y,
            (v[2] - mu) * invs * g0.z + b0.z, (v[3] - mu) * invs * g0.w + b0.w,
            (v[4] - mu) * invs * g1v.x + b1v.x, (v[5] - mu) * invs * g1v.y + b1v.y,
            (v[6] - mu) * invs * g1v.z + b1v.z, (v[7] - mu) * invs * g1v.w + b1v.w };
        uint4 st;
        asm("v_cvt_pk_bf16_f32 %0, %1, %2" : "=v"(st.x) : "v"(o_[0]), "v"(o_[1]));
        asm("v_cvt_pk_bf16_f32 %0, %1, %2" : "=v"(st.y) : "v"(o_[2]), "v"(o_[3]));
        asm("v_cvt_pk_bf16_f32 %0, %1, %2" : "=v"(st.z) : "v"(o_[4]), "v"(o_[5]));
        asm("v_cvt_pk_bf16_f32 %0, %1, %2" : "=v"(st.w) : "v"(o_[6]), "v"(o_[7]));
        *reinterpret_cast<uint4*>(y + (size_t)row * DIMM + lane * 8) = st;
    }
}

// ---------------- wave-per-row layernorm (row = 512), output bf16 ----------------
template<typename TIN>
__global__ __launch_bounds__(256) void ln_fast(const TIN* __restrict__ x,
                                               const float* __restrict__ g,
                                               const float* __restrict__ bta,
                                               __bf16* __restrict__ y) {
    const int row = blockIdx.x * 4 + (threadIdx.x >> 6);
    const int lane = threadIdx.x & 63;
    float v[8];
    if constexpr (sizeof(TIN) == 4) {
        const float4* xr = (const float4*)((const float*)x + (size_t)row * DIMM + lane * 8);
        float4 a = xr[0], bq = xr[1];
        v[0] = a.x; v[1] = a.y; v[2] = a.z; v[3] = a.w;
        v[4] = bq.x; v[5] = bq.y; v[6] = bq.z; v[7] = bq.w;
    } else {
        bf16x8 a = *reinterpret_cast<const bf16x8*>((const __bf16*)x + (size_t)row * DIMM + lane * 8);
#pragma unroll
        for (int e = 0; e < 8; ++e) v[e] = (float)a[e];
    }
    float s = 0.f, sq = 0.f;
#pragma unroll
    for (int e = 0; e < 8; ++e) { s += v[e]; sq += v[e] * v[e]; }
    for (int o = 32; o; o >>= 1) { s += __shfl_xor(s, o); sq += __shfl_xor(sq, o); }
    const float mu = s * (1.f / DIMM);
    const float invs = rsqrtf(sq * (1.f / DIMM) - mu * mu + 1e-5f);
    const float4* gp = (const float4*)(g + lane * 8);
    const float4* bp = (const float4*)(bta + lane * 8);
    float4 g0 = gp[0], g1 = gp[1], b0 = bp[0], b1 = bp[1];
    float o_[8] = {
        (v[0] - mu) * invs * g0.x + b0.x, (v[1] - mu) * invs * g0.y + b0.y,
        (v[2] - mu) * invs * g0.z + b0.z, (v[3] - mu) * invs * g0.w + b0.w,
        (v[4] - mu) * invs * g1.x + b1.x, (v[5] - mu) * invs * g1.y + b1.y,
        (v[6] - mu) * invs * g1.z + b1.z, (v[7] - mu) * invs * g1.w + b1.w };
    uint4 st;
    asm("v_cvt_pk_bf16_f32 %0, %1, %2" : "=v"(st.x) : "v"(o_[0]), "v"(o_[1]));
    asm("v_cvt_pk_bf16_f32 %0, %1, %2" : "=v"(st.y) : "v"(o_[2]), "v"(o_[3]));
    asm("v_cvt_pk_bf16_f32 %0, %1, %2" : "=v"(st.z) : "v"(o_[4]), "v"(o_[5]));
    asm("v_cvt_pk_bf16_f32 %0, %1, %2" : "=v"(st.w) : "v"(o_[6]), "v"(o_[7]));
    *reinterpret_cast<uint4*>(y + (size_t)row * DIMM + lane * 8) = st;
}

// ---------------- LDS-staged MFMA GEMM (round-6 exact compute; optional split output) ----------------
// VSPLIT (gemm1): cols<1024 -> qk[row*1024+col]; cols>=1024 -> vt[bh][d][tok] scatter.
template<int NCOLS, bool BIAS, bool OUT_F32, bool VSPLIT>
__global__ __launch_bounds__(256) void gemm_lds(const __bf16* __restrict__ A,
                                                const __bf16* __restrict__ Wt,
                                                const float* __restrict__ bias,
                                                __bf16* __restrict__ outb,
                                                float* __restrict__ outf,
                                                __bf16* __restrict__ vt) {
    const int K = DIMM;
    __shared__ __align__(16) __bf16 As[2][4096];
    __shared__ __align__(16) __bf16 Bs[2][4096];

    const int tid = threadIdx.x;
    const int w = tid >> 6, lane = tid & 63;
    const int m = lane & 15, g = lane >> 4;
    const int mi = w >> 1, ni = w & 1;

    const int trow = tid >> 2;
    const int tc = tid & 3;
    const int sc = (tc ^ ((trow >> 1) & 3)) * 8;
    const __bf16* a0 = A  + (size_t)(blockIdx.x * 128 + trow) * K + sc;
    const __bf16* a1 = a0 + (size_t)64 * K;
    const __bf16* b0 = Wt + (size_t)(blockIdx.y * 128 + trow) * K + sc;
    const __bf16* b1 = b0 + (size_t)64 * K;

    f32x4 acc[4][4] = {};

    GLOAD_LDS16(a0, (char*)As[0] + tid * 16);
    GLOAD_LDS16(a1, (char*)As[0] + 4096 + tid * 16);
    GLOAD_LDS16(b0, (char*)Bs[0] + tid * 16);
    GLOAD_LDS16(b1, (char*)Bs[0] + 4096 + tid * 16);

    int cur = 0;
    for (int k0 = 0; k0 < K; k0 += 32) {
        __syncthreads();
        if (k0 + 32 < K) {
            GLOAD_LDS16(a0 + k0 + 32, (char*)As[cur ^ 1] + tid * 16);
            GLOAD_LDS16(a1 + k0 + 32, (char*)As[cur ^ 1] + 4096 + tid * 16);
            GLOAD_LDS16(b0 + k0 + 32, (char*)Bs[cur ^ 1] + tid * 16);
            GLOAD_LDS16(b1 + k0 + 32, (char*)Bs[cur ^ 1] + 4096 + tid * 16);
        }

        const char* Ab = (const char*)As[cur];
        const char* Bb = (const char*)Bs[cur];
        bf16x8 af[4], bfr[4];
#pragma unroll
        for (int i = 0; i < 4; ++i) {
            const int ra = mi * 64 + i * 16 + m;
            af[i] = *reinterpret_cast<const bf16x8*>(Ab + ra * 64 + ((g ^ ((ra >> 1) & 3)) << 4));
        }
#pragma unroll
        for (int j = 0; j < 4; ++j) {
            const int rb = ni * 64 + j * 16 + m;
            bfr[j] = *reinterpret_cast<const bf16x8*>(Bb + rb * 64 + ((g ^ ((rb >> 1) & 3)) << 4));
        }
#pragma unroll
        for (int i = 0; i < 4; ++i)
#pragma unroll
            for (int j = 0; j < 4; ++j)
                acc[i][j] = __builtin_amdgcn_mfma_f32_16x16x32_bf16(af[i], bfr[j], acc[i][j], 0, 0, 0);
        cur ^= 1;
    }

    const int orow0 = blockIdx.x * 128 + mi * 64 + g * 4;
    const int ocol0 = blockIdx.y * 128 + ni * 64;
#pragma unroll
    for (int i = 0; i < 4; ++i)
#pragma unroll
        for (int j = 0; j < 4; ++j)
#pragma unroll
            for (int r = 0; r < 4; ++r) {
                int row = orow0 + i * 16 + r;
                int col = ocol0 + j * 16 + m;
                float v = acc[i][j][r];
                if (BIAS) v += bias[col];
                if (VSPLIT) {
                    if (col < 1024) {
                        outb[(size_t)row * 1024 + col] = (__bf16)v;
                    } else {
                        const int vc = col - 1024;
                        vt[(size_t)(((row >> 10) * 8 + (vc >> 6)) * 64 + (vc & 63)) * 1024
                           + (row & 1023)] = (__bf16)v;
                    }
                } else if (OUT_F32) {
                    outf[(size_t)row * NCOLS + col] = v;
                } else {
                    outb[(size_t)row * NCOLS + col] = (__bf16)v;
                }
            }
}

// ---------------- MFMA flash attention (r16-verified kernel; QK/VT sources) ----------------
// grid (64 bh, 16 qt); 256 threads = 4 waves, 16 q-rows/wave; DMA dbuf staging.
__global__ __launch_bounds__(256, 4) void attn_mfma(const __bf16* __restrict__ qk,
                                                    const __bf16* __restrict__ vtg,
                                                    __bf16* __restrict__ out) {
    const int bh = blockIdx.x, qt = blockIdx.y;
    const int b = bh >> 3, h = bh & 7;
    const int tid = threadIdx.x;
    const int w = tid >> 6, lane = tid & 63;
    const int g = lane >> 4, m = lane & 15;

    __shared__ __align__(16) __bf16 Kb[2][4096];   // [64 key][64 d], chunk c of row r at c^(r&7)
    __shared__ __align__(16) __bf16 Vb[2][4096];   // [64 d][64 key], same layout
    __shared__ __align__(16) __bf16 Pl[4][1024];   // per-wave [16 q][64 key]

    bf16x8 qf[2];
    {
        const __bf16* qp = qk + (size_t)(b * SEQ + qt * 64 + w * 16 + m) * 1024 + h * 64 + g * 8;
        qf[0] = *reinterpret_cast<const bf16x8*>(qp);
        qf[1] = *reinterpret_cast<const bf16x8*>(qp + 32);
#pragma unroll
        for (int e = 0; e < 8; ++e) {
            qf[0][e] = (__bf16)((float)qf[0][e] * 0.125f);
            qf[1][e] = (__bf16)((float)qf[1][e] * 0.125f);
        }
    }

    const int sr = tid >> 3;            // 0..31
    const int sp = tid & 7;             // 0..7
    const int scn = sp ^ (sr & 7);
    const __bf16* ksrc = qk + (size_t)(b * SEQ + sr) * 1024 + 512 + h * 64 + scn * 8;
    const __bf16* vsrc = vtg + (size_t)(bh * 64 + sr) * SEQ + scn * 8;
    const size_t kstep = (size_t)64 * 1024;

    auto stage = [&](int bb, int t) {
        GLOAD_LDS16(ksrc + (size_t)t * kstep,                      (char*)Kb[bb] + tid * 16);
        GLOAD_LDS16(ksrc + (size_t)t * kstep + (size_t)32 * 1024,  (char*)Kb[bb] + 4096 + tid * 16);
        GLOAD_LDS16(vsrc + t * 64,                                 (char*)Vb[bb] + tid * 16);
        GLOAD_LDS16(vsrc + t * 64 + (size_t)32 * SEQ,              (char*)Vb[bb] + 4096 + tid * 16);
    };

    f32x4 oa[4] = {};
    float mrun = -1e30f, lrun = 0.f;
    char* pw = (char*)Pl[w] + m * 128;
    const int psw = (m & 7) << 4;

    stage(0, 0);
    int cur = 0;
    for (int t = 0; t < 16; ++t) {
        __syncthreads();                 // drains buf[cur] DMA; buf[cur^1] fully consumed
        if (t < 15) stage(cur ^ 1, t + 1);

        const char* kb = (const char*)Kb[cur];
        const char* vb = (const char*)Vb[cur];

        // ---- S^T = K @ Q^T ----
        f32x4 sa[4];
#pragma unroll
        for (int i = 0; i < 4; ++i) sa[i] = (f32x4){0.f, 0.f, 0.f, 0.f};
#pragma unroll
        for (int kc = 0; kc < 2; ++kc) {
            const int cp = ((kc * 4 + g) ^ (m & 7)) << 4;
#pragma unroll
            for (int i = 0; i < 4; ++i) {
                bf16x8 kf = *reinterpret_cast<const bf16x8*>(kb + (i * 16 + m) * 128 + cp);
                sa[i] = __builtin_amdgcn_mfma_f32_16x16x32_bf16(kf, qf[kc], sa[i], 0, 0, 0);
            }
        }

        // ---- online softmax (lane owns q=m; keys i*16+g*4+r in-lane) ----
        {
            float mx = -1e30f;
#pragma unroll
            for (int i = 0; i < 4; ++i)
#pragma unroll
                for (int r = 0; r < 4; ++r) mx = fmaxf(mx, sa[i][r]);
            mx = fmaxf(mx, __shfl_xor(mx, 16));
            mx = fmaxf(mx, __shfl_xor(mx, 32));
            const float mnew = fmaxf(mrun, mx);
            float p[4][4];
            float ps = 0.f;
#pragma unroll
            for (int i = 0; i < 4; ++i)
#pragma unroll
                for (int r = 0; r < 4; ++r) { p[i][r] = __expf(sa[i][r] - mnew); ps += p[i][r]; }
            ps += __shfl_xor(ps, 16);
            ps += __shfl_xor(ps, 32);
            const float al = __expf(mrun - mnew);
            mrun = mnew;
            lrun = lrun * al + ps;
#pragma unroll
            for (int i = 0; i < 4; ++i)
#pragma unroll
                for (int r = 0; r < 4; ++r) oa[i][r] *= al;
#pragma unroll
            for (int i = 0; i < 4; ++i) {
                uint2 pk;
                asm("v_cvt_pk_bf16_f32 %0, %1, %2" : "=v"(pk.x) : "v"(p[i][0]), "v"(p[i][1]));
                asm("v_cvt_pk_bf16_f32 %0, %1, %2" : "=v"(pk.y) : "v"(p[i][2]), "v"(p[i][3]));
                *reinterpret_cast<uint2*>(pw + ((i * 32 + g * 8) ^ psw)) = pk;
            }
        }

        // ---- P fragments (per-wave LDS, same-wave ordering) ----
        bf16x8 pf[2];
#pragma unroll
        for (int kc = 0; kc < 2; ++kc)
            pf[kc] = *reinterpret_cast<const bf16x8*>(pw + ((kc * 64 + g * 16) ^ psw));

        // ---- O^T += V^T @ P^T (same cp swizzle as K reads) ----
#pragma unroll
        for (int kc = 0; kc < 2; ++kc) {
            const int cp = ((kc * 4 + g) ^ (m & 7)) << 4;
#pragma unroll
            for (int i = 0; i < 4; ++i) {
                bf16x8 vf = *reinterpret_cast<const bf16x8*>(vb + (i * 16 + m) * 128 + cp);
                oa[i] = __builtin_amdgcn_mfma_f32_16x16x32_bf16(vf, pf[kc], oa[i], 0, 0, 0);
            }
        }

        cur ^= 1;
    }

    // ---- epilogue (verified) ----
    const float inv = 1.0f / lrun;
    unsigned int* orow = (unsigned int*)(out +
        (size_t)(b * SEQ + qt * 64 + w * 16 + m) * DIMM + h * 64);
#pragma unroll
    for (int i = 0; i < 4; ++i)
#pragma unroll
        for (int rp = 0; rp < 2; ++rp) {
            float o0 = oa[i][2 * rp] * inv, o1 = oa[i][2 * rp + 1] * inv;
            unsigned int pk;
            asm("v_cvt_pk_bf16_f32 %0, %1, %2" : "=v"(pk) : "v"(o0), "v"(o1));
            orow[i * 8 + g * 2 + rp] = pk;
        }
}

// ---------------- launch ----------------
extern "C" void kernel_launch(void* const* d_in, const int* in_sizes, int n_in,
                              void* d_out, int out_size, void* d_ws, size_t ws_size,
                              hipStream_t stream) {
    const float* x     = (const float*)d_in[0];
    const float* g1    = (const float*)d_in[1];
    const float* b1    = (const float*)d_in[2];
    const float* W_qkv = (const float*)d_in[3];
    const float* g2    = (const float*)d_in[4];
    const float* b2    = (const float*)d_in[5];
    const float* W_out = (const float*)d_in[6];
    const float* b_out = (const float*)d_in[7];
    float* out = (float*)d_out;

    char* ws = (char*)d_ws;
    float* part   = (float*)(ws);                                // 320 floats
    __bf16* Wq1 = (__bf16*)(ws + 4096);                          // [1536,512]
    __bf16* Wq2 = (__bf16*)(ws + 4096 + 1572864);                // [512,512]
    __bf16* Xln = (__bf16*)(ws + 2101248);                       // [8192,512] (LN1 out; reused for LN2 out)
    __bf16* QK  = (__bf16*)(ws + 10489856);                      // [8192,1024] (Q|K)
    __bf16* VT  = (__bf16*)(ws + 27267072);                      // [64 bh][64 d][1024 tok]
    __bf16* AO  = (__bf16*)(ws + 35655680);                      // [8192,512]
    // total = 44,044,288 B (proven footprint)

    absum_all<<<320, 256, 0, stream>>>(W_qkv, W_out, part);
    quant_ln<<<3072, 256, 0, stream>>>(W_qkv, W_out, part, x, g1, b1, Wq1, Wq2, Xln);
    gemm_lds<TRIPLE, false, false, true><<<dim3(64, 12), 256, 0, stream>>>(Xln, Wq1, nullptr, QK, nullptr, VT);
    attn_mfma<<<dim3(64, 16), 256, 0, stream>>>(QK, VT, AO);
    ln_fast<__bf16><<<MROWS / 4, 256, 0, stream>>>(AO, g2, b2, Xln);
    gemm_lds<DIMM, true, true, false><<<dim3(64, 4), 256, 0, stream>>>(Xln, Wq2, b_out, nullptr, out, nullptr);
}

// Round 20
// 85.361 us; speedup vs baseline: 1.0983x; 1.0902x over previous
//
#include <hip/hip_runtime.h>
#include <hip/hip_bf16.h>

typedef __bf16 bf16x8 __attribute__((ext_vector_type(8)));
typedef float  f32x4  __attribute__((ext_vector_type(4)));

#define SEQ   1024
#define BATCH 8
#define DIMM  512
#define HEADS 8
#define DHEAD 64
#define TRIPLE 1536
#define MROWS (BATCH*SEQ)   // 8192

#define GLOAD_LDS16(g, l) __builtin_amdgcn_global_load_lds( \
    (const __attribute__((address_space(1))) void*)(const void*)(g), \
    (__attribute__((address_space(3))) void*)(void*)(l), 16, 0, 0)

// ---------------- merged |w| partial sums ----------------
__global__ __launch_bounds__(256) void absum_all(const float* __restrict__ w1,
                                                 const float* __restrict__ w2,
                                                 float* __restrict__ part) {
    const int bid = blockIdx.x, tid = threadIdx.x;
    float s = 0.f;
    if (bid < 256) {
        const float4* p = (const float4*)w1;
        for (int i = bid * 256 + tid; i < 196608; i += 65536) {
            float4 v = p[i];
            s += fabsf(v.x) + fabsf(v.y) + fabsf(v.z) + fabsf(v.w);
        }
    } else {
        const float4* p = (const float4*)w2;
        for (int i = (bid - 256) * 256 + tid; i < 65536; i += 16384) {
            float4 v = p[i];
            s += fabsf(v.x) + fabsf(v.y) + fabsf(v.z) + fabsf(v.w);
        }
    }
    for (int o = 32; o; o >>= 1) s += __shfl_down(s, o);
    __shared__ float red[4];
    if (!(tid & 63)) red[tid >> 6] = s;
    __syncthreads();
    if (tid == 0) part[bid] = red[0] + red[1] + red[2] + red[3];
}

// ---------------- fused: ternary quantize (blocks 0..1023) || LN1 (blocks 1024..3071) ----------------
// (r18-verified)
__global__ __launch_bounds__(256) void quant_ln(const float* __restrict__ w1,
                                                const float* __restrict__ w2,
                                                const float* __restrict__ part,
                                                const float* __restrict__ x,
                                                const float* __restrict__ g1,
                                                const float* __restrict__ b1,
                                                __bf16* __restrict__ o1,
                                                __bf16* __restrict__ o2,
                                                __bf16* __restrict__ y) {
    const int bid = blockIdx.x, tid = threadIdx.x;
    if (bid < 1024) {
        float acc = 0.f;
        if (bid < 768) acc = part[tid];
        else if (tid < 64) acc = part[256 + tid];
        for (int o = 32; o; o >>= 1) acc += __shfl_down(acc, o);
        __shared__ float red[4];
        if (!(tid & 63)) red[tid >> 6] = acc;
        __syncthreads();
        const float tot = red[0] + red[1] + red[2] + red[3];
        const float s = (bid < 768) ? tot / 786432.0f : tot / 262144.0f;
        const float inv = 1.f / (s + 1e-6f);
        const float* w; __bf16* o; int idx;
        if (bid < 768) { w = w1; o = o1; idx = (bid * 256 + tid) * 4; }
        else           { w = w2; o = o2; idx = ((bid - 768) * 256 + tid) * 4; }
        float4 v = *reinterpret_cast<const float4*>(w + idx);
        o[idx + 0] = (__bf16)(rintf(fminf(1.f, fmaxf(-1.f, v.x * inv))) * s);
        o[idx + 1] = (__bf16)(rintf(fminf(1.f, fmaxf(-1.f, v.y * inv))) * s);
        o[idx + 2] = (__bf16)(rintf(fminf(1.f, fmaxf(-1.f, v.z * inv))) * s);
        o[idx + 3] = (__bf16)(rintf(fminf(1.f, fmaxf(-1.f, v.w * inv))) * s);
    } else {
        const int row = (bid - 1024) * 4 + (tid >> 6);
        const int lane = tid & 63;
        const float4* xr = (const float4*)(x + (size_t)row * DIMM + lane * 8);
        float4 a = xr[0], bq = xr[1];
        float v[8] = {a.x, a.y, a.z, a.w, bq.x, bq.y, bq.z, bq.w};
        float s = 0.f, sq = 0.f;
#pragma unroll
        for (int e = 0; e < 8; ++e) { s += v[e]; sq += v[e] * v[e]; }
        for (int o = 32; o; o >>= 1) { s += __shfl_xor(s, o); sq += __shfl_xor(sq, o); }
        const float mu = s * (1.f / DIMM);
        const float invs = rsqrtf(sq * (1.f / DIMM) - mu * mu + 1e-5f);
        const float4* gp = (const float4*)(g1 + lane * 8);
        const float4* bp = (const float4*)(b1 + lane * 8);
        float4 g0 = gp[0], g1v = gp[1], b0 = bp[0], b1v = bp[1];
        float o_[8] = {
            (v[0] - mu) * invs * g0.x + b0.x, (v[1] - mu) * invs * g0.y + b0.y,
            (v[2] - mu) * invs * g0.z + b0.z, (v[3] - mu) * invs * g0.w + b0.w,
            (v[4] - mu) * invs * g1v.x + b1v.x, (v[5] - mu) * invs * g1v.y + b1v.y,
            (v[6] - mu) * invs * g1v.z + b1v.z, (v[7] - mu) * invs * g1v.w + b1v.w };
        uint4 st;
        asm("v_cvt_pk_bf16_f32 %0, %1, %2" : "=v"(st.x) : "v"(o_[0]), "v"(o_[1]));
        asm("v_cvt_pk_bf16_f32 %0, %1, %2" : "=v"(st.y) : "v"(o_[2]), "v"(o_[3]));
        asm("v_cvt_pk_bf16_f32 %0, %1, %2" : "=v"(st.z) : "v"(o_[4]), "v"(o_[5]));
        asm("v_cvt_pk_bf16_f32 %0, %1, %2" : "=v"(st.w) : "v"(o_[6]), "v"(o_[7]));
        *reinterpret_cast<uint4*>(y + (size_t)row * DIMM + lane * 8) = st;
    }
}

// ---------------- wave-per-row layernorm (row = 512), output bf16 ----------------
template<typename TIN>
__global__ __launch_bounds__(256) void ln_fast(const TIN* __restrict__ x,
                                               const float* __restrict__ g,
                                               const float* __restrict__ bta,
                                               __bf16* __restrict__ y) {
    const int row = blockIdx.x * 4 + (threadIdx.x >> 6);
    const int lane = threadIdx.x & 63;
    float v[8];
    if constexpr (sizeof(TIN) == 4) {
        const float4* xr = (const float4*)((const float*)x + (size_t)row * DIMM + lane * 8);
        float4 a = xr[0], bq = xr[1];
        v[0] = a.x; v[1] = a.y; v[2] = a.z; v[3] = a.w;
        v[4] = bq.x; v[5] = bq.y; v[6] = bq.z; v[7] = bq.w;
    } else {
        bf16x8 a = *reinterpret_cast<const bf16x8*>((const __bf16*)x + (size_t)row * DIMM + lane * 8);
#pragma unroll
        for (int e = 0; e < 8; ++e) v[e] = (float)a[e];
    }
    float s = 0.f, sq = 0.f;
#pragma unroll
    for (int e = 0; e < 8; ++e) { s += v[e]; sq += v[e] * v[e]; }
    for (int o = 32; o; o >>= 1) { s += __shfl_xor(s, o); sq += __shfl_xor(sq, o); }
    const float mu = s * (1.f / DIMM);
    const float invs = rsqrtf(sq * (1.f / DIMM) - mu * mu + 1e-5f);
    const float4* gp = (const float4*)(g + lane * 8);
    const float4* bp = (const float4*)(bta + lane * 8);
    float4 g0 = gp[0], g1 = gp[1], b0 = bp[0], b1 = bp[1];
    float o_[8] = {
        (v[0] - mu) * invs * g0.x + b0.x, (v[1] - mu) * invs * g0.y + b0.y,
        (v[2] - mu) * invs * g0.z + b0.z, (v[3] - mu) * invs * g0.w + b0.w,
        (v[4] - mu) * invs * g1.x + b1.x, (v[5] - mu) * invs * g1.y + b1.y,
        (v[6] - mu) * invs * g1.z + b1.z, (v[7] - mu) * invs * g1.w + b1.w };
    uint4 st;
    asm("v_cvt_pk_bf16_f32 %0, %1, %2" : "=v"(st.x) : "v"(o_[0]), "v"(o_[1]));
    asm("v_cvt_pk_bf16_f32 %0, %1, %2" : "=v"(st.y) : "v"(o_[2]), "v"(o_[3]));
    asm("v_cvt_pk_bf16_f32 %0, %1, %2" : "=v"(st.z) : "v"(o_[4]), "v"(o_[5]));
    asm("v_cvt_pk_bf16_f32 %0, %1, %2" : "=v"(st.w) : "v"(o_[6]), "v"(o_[7]));
    *reinterpret_cast<uint4*>(y + (size_t)row * DIMM + lane * 8) = st;
}

// ---------------- LDS-staged MFMA GEMM (round-6 exact) ----------------
template<int NCOLS, bool BIAS, bool OUT_F32>
__global__ __launch_bounds__(256) void gemm_lds(const __bf16* __restrict__ A,
                                                const __bf16* __restrict__ Wt,
                                                const float* __restrict__ bias,
                                                __bf16* __restrict__ outb,
                                                float* __restrict__ outf) {
    const int K = DIMM;
    __shared__ __align__(16) __bf16 As[2][4096];
    __shared__ __align__(16) __bf16 Bs[2][4096];

    const int tid = threadIdx.x;
    const int w = tid >> 6, lane = tid & 63;
    const int m = lane & 15, g = lane >> 4;
    const int mi = w >> 1, ni = w & 1;

    const int trow = tid >> 2;
    const int tc = tid & 3;
    const int sc = (tc ^ ((trow >> 1) & 3)) * 8;
    const __bf16* a0 = A  + (size_t)(blockIdx.x * 128 + trow) * K + sc;
    const __bf16* a1 = a0 + (size_t)64 * K;
    const __bf16* b0 = Wt + (size_t)(blockIdx.y * 128 + trow) * K + sc;
    const __bf16* b1 = b0 + (size_t)64 * K;

    f32x4 acc[4][4] = {};

    GLOAD_LDS16(a0, (char*)As[0] + tid * 16);
    GLOAD_LDS16(a1, (char*)As[0] + 4096 + tid * 16);
    GLOAD_LDS16(b0, (char*)Bs[0] + tid * 16);
    GLOAD_LDS16(b1, (char*)Bs[0] + 4096 + tid * 16);

    int cur = 0;
    for (int k0 = 0; k0 < K; k0 += 32) {
        __syncthreads();
        if (k0 + 32 < K) {
            GLOAD_LDS16(a0 + k0 + 32, (char*)As[cur ^ 1] + tid * 16);
            GLOAD_LDS16(a1 + k0 + 32, (char*)As[cur ^ 1] + 4096 + tid * 16);
            GLOAD_LDS16(b0 + k0 + 32, (char*)Bs[cur ^ 1] + tid * 16);
            GLOAD_LDS16(b1 + k0 + 32, (char*)Bs[cur ^ 1] + 4096 + tid * 16);
        }

        const char* Ab = (const char*)As[cur];
        const char* Bb = (const char*)Bs[cur];
        bf16x8 af[4], bfr[4];
#pragma unroll
        for (int i = 0; i < 4; ++i) {
            const int ra = mi * 64 + i * 16 + m;
            af[i] = *reinterpret_cast<const bf16x8*>(Ab + ra * 64 + ((g ^ ((ra >> 1) & 3)) << 4));
        }
#pragma unroll
        for (int j = 0; j < 4; ++j) {
            const int rb = ni * 64 + j * 16 + m;
            bfr[j] = *reinterpret_cast<const bf16x8*>(Bb + rb * 64 + ((g ^ ((rb >> 1) & 3)) << 4));
        }
#pragma unroll
        for (int i = 0; i < 4; ++i)
#pragma unroll
            for (int j = 0; j < 4; ++j)
                acc[i][j] = __builtin_amdgcn_mfma_f32_16x16x32_bf16(af[i], bfr[j], acc[i][j], 0, 0, 0);
        cur ^= 1;
    }

    const int orow0 = blockIdx.x * 128 + mi * 64 + g * 4;
    const int ocol0 = blockIdx.y * 128 + ni * 64;
#pragma unroll
    for (int i = 0; i < 4; ++i)
#pragma unroll
        for (int j = 0; j < 4; ++j)
#pragma unroll
            for (int r = 0; r < 4; ++r) {
                int row = orow0 + i * 16 + r;
                int col = ocol0 + j * 16 + m;
                float v = acc[i][j][r];
                if (BIAS) v += bias[col];
                if (OUT_F32) outf[(size_t)row * NCOLS + col] = v;
                else         outb[(size_t)row * NCOLS + col] = (__bf16)v;
            }
}

// ---------------- MFMA flash attention (r12-verified body, NO setprio) ----------------
// grid (64 bh, 8 qt); 256 threads = 4 waves, 32 q-rows/wave (two 16-row halves).
// lin%8 == h -> same-XCD K/V sharing. Reg-staged K/V with both-side swizzles,
// 2 barriers/tile, t+1 reg prefetch. NOTE: s_setprio around these MFMA clusters
// corrupted results twice (r9, r19) on this toolchain — do not re-add.
__global__ __launch_bounds__(256, 2) void attn_mfma(const __bf16* __restrict__ qkv,
                                                    __bf16* __restrict__ out) {
    const int qt = blockIdx.y, bh = blockIdx.x;
    const int b = bh >> 3, h = bh & 7;
    const int tid = threadIdx.x;
    const int w = tid >> 6, lane = tid & 63;
    const int g = lane >> 4, m = lane & 15;

    __shared__ __align__(16) __bf16 Kb[4096];      // [64 key][64 d], chunk c at c^(key&7)
    __shared__ __align__(16) __bf16 Vt[4096];      // [64 d][64 key], chunk c at c^((d>>3)^(d&7))
    __shared__ __align__(16) __bf16 Pl[4][2048];   // per-wave [32 q][64 key], chunk c at c^(q&7)

    bf16x8 qf[2][2];
    {
        const __bf16* qp = qkv + (size_t)(b * SEQ + qt * 128 + w * 32 + m) * TRIPLE + h * 64 + g * 8;
#pragma unroll
        for (int hf = 0; hf < 2; ++hf) {
            qf[hf][0] = *reinterpret_cast<const bf16x8*>(qp + (size_t)hf * 16 * TRIPLE);
            qf[hf][1] = *reinterpret_cast<const bf16x8*>(qp + (size_t)hf * 16 * TRIPLE + 32);
#pragma unroll
            for (int e = 0; e < 8; ++e) {
                qf[hf][0][e] = (__bf16)((float)qf[hf][0][e] * 0.125f);
                qf[hf][1][e] = (__bf16)((float)qf[hf][1][e] * 0.125f);
            }
        }
    }

    const int srow = tid >> 3;          // 0..31
    const int sc   = tid & 7;           // 0..7
    const size_t rbase = (size_t)(b * SEQ + srow) * TRIPLE + h * 64 + sc * 8;
    const __bf16* k0s = qkv + rbase + DIMM;
    const __bf16* v0s = qkv + rbase + 2 * DIMM;
    const __bf16* k1s = k0s + (size_t)32 * TRIPLE;
    const __bf16* v1s = v0s + (size_t)32 * TRIPLE;
    const int kstep = 64 * TRIPLE;

    char* kw0 = (char*)Kb + srow * 128 + ((sc ^ (srow & 7)) << 4);
    char* kw1 = kw0 + 32 * 128;
    char* vbp = (char*)Vt;

    f32x4 oa[2][4] = {};
    float mrun[2] = {-1e30f, -1e30f}, lrun[2] = {0.f, 0.f};

    uint4 k0c = *reinterpret_cast<const uint4*>(k0s);
    uint4 k1c = *reinterpret_cast<const uint4*>(k1s);
    uint4 v0c = *reinterpret_cast<const uint4*>(v0s);
    uint4 v1c = *reinterpret_cast<const uint4*>(v1s);
    uint4 k0n = {}, k1n = {}, v0n = {}, v1n = {};

    for (int t = 0; t < 16; ++t) {
        __syncthreads();

        *reinterpret_cast<bf16x8*>(kw0) = *reinterpret_cast<bf16x8*>(&k0c);
        *reinterpret_cast<bf16x8*>(kw1) = *reinterpret_cast<bf16x8*>(&k1c);
        {
            bf16x8 va = *reinterpret_cast<bf16x8*>(&v0c);
            bf16x8 vb = *reinterpret_cast<bf16x8*>(&v1c);
#pragma unroll
            for (int e = 0; e < 8; ++e) {
                const int dro = (sc * 8 + e) * 128;
                const int sw = ((sc ^ e) & 7) << 4;
                *(__bf16*)(vbp + dro + ((srow * 2) ^ sw))        = va[e];
                *(__bf16*)(vbp + dro + (((srow + 32) * 2) ^ sw)) = vb[e];
            }
        }
        __syncthreads();

        if (t < 15) {
            k0n = *reinterpret_cast<const uint4*>(k0s + (size_t)(t + 1) * kstep);
            k1n = *reinterpret_cast<const uint4*>(k1s + (size_t)(t + 1) * kstep);
            v0n = *reinterpret_cast<const uint4*>(v0s + (size_t)(t + 1) * kstep);
            v1n = *reinterpret_cast<const uint4*>(v1s + (size_t)(t + 1) * kstep);
        }

        // ---- S^T = K @ Q^T ----
        const char* kb = (const char*)Kb;
        f32x4 sa[2][4];
#pragma unroll
        for (int hf = 0; hf < 2; ++hf)
#pragma unroll
            for (int i = 0; i < 4; ++i) sa[hf][i] = (f32x4){0.f, 0.f, 0.f, 0.f};
#pragma unroll
        for (int kc = 0; kc < 2; ++kc) {
            const int cp = ((kc * 4 + g) ^ (m & 7)) << 4;
#pragma unroll
            for (int i = 0; i < 4; ++i) {
                bf16x8 kf = *reinterpret_cast<const bf16x8*>(kb + (i * 16 + m) * 128 + cp);
                sa[0][i] = __builtin_amdgcn_mfma_f32_16x16x32_bf16(kf, qf[0][kc], sa[0][i], 0, 0, 0);
                sa[1][i] = __builtin_amdgcn_mfma_f32_16x16x32_bf16(kf, qf[1][kc], sa[1][i], 0, 0, 0);
            }
        }

        // ---- online softmax per half + P pack/store ----
        char* pw = (char*)Pl[w] + m * 128;
        const int psw = (m & 7) << 4;
#pragma unroll
        for (int hf = 0; hf < 2; ++hf) {
            float mx = -1e30f;
#pragma unroll
            for (int i = 0; i < 4; ++i)
#pragma unroll
                for (int r = 0; r < 4; ++r) mx = fmaxf(mx, sa[hf][i][r]);
            mx = fmaxf(mx, __shfl_xor(mx, 16));
            mx = fmaxf(mx, __shfl_xor(mx, 32));
            const float mnew = fmaxf(mrun[hf], mx);
            float p[4][4];
            float ps = 0.f;
#pragma unroll
            for (int i = 0; i < 4; ++i)
#pragma unroll
                for (int r = 0; r < 4; ++r) { p[i][r] = __expf(sa[hf][i][r] - mnew); ps += p[i][r]; }
            ps += __shfl_xor(ps, 16);
            ps += __shfl_xor(ps, 32);
            const float al = __expf(mrun[hf] - mnew);
            mrun[hf] = mnew;
            lrun[hf] = lrun[hf] * al + ps;
#pragma unroll
            for (int i = 0; i < 4; ++i)
#pragma unroll
                for (int r = 0; r < 4; ++r) oa[hf][i][r] *= al;
#pragma unroll
            for (int i = 0; i < 4; ++i) {
                uint2 pk;
                asm("v_cvt_pk_bf16_f32 %0, %1, %2" : "=v"(pk.x) : "v"(p[i][0]), "v"(p[i][1]));
                asm("v_cvt_pk_bf16_f32 %0, %1, %2" : "=v"(pk.y) : "v"(p[i][2]), "v"(p[i][3]));
                *reinterpret_cast<uint2*>(pw + hf * 16 * 128 + ((i * 32 + g * 8) ^ psw)) = pk;
            }
        }

        // ---- P fragments ----
        bf16x8 pf[2][2];
#pragma unroll
        for (int hf = 0; hf < 2; ++hf)
#pragma unroll
            for (int kc = 0; kc < 2; ++kc)
                pf[hf][kc] = *reinterpret_cast<const bf16x8*>(
                    pw + hf * 16 * 128 + ((kc * 64 + g * 16) ^ psw));

        // ---- O^T += V^T @ P^T ----
#pragma unroll
        for (int kc = 0; kc < 2; ++kc)
#pragma unroll
            for (int i = 0; i < 4; ++i) {
                const int sv = ((i * 2 + (m >> 3)) ^ (m & 7)) & 7;
                bf16x8 vf = *reinterpret_cast<const bf16x8*>(
                    vbp + (i * 16 + m) * 128 + (((kc * 4 + g) ^ sv) << 4));
                oa[0][i] = __builtin_amdgcn_mfma_f32_16x16x32_bf16(vf, pf[0][kc], oa[0][i], 0, 0, 0);
                oa[1][i] = __builtin_amdgcn_mfma_f32_16x16x32_bf16(vf, pf[1][kc], oa[1][i], 0, 0, 0);
            }

        k0c = k0n; k1c = k1n; v0c = v0n; v1c = v1n;
    }

#pragma unroll
    for (int hf = 0; hf < 2; ++hf) {
        const float inv = 1.0f / lrun[hf];
        unsigned int* orow = (unsigned int*)(out +
            (size_t)(b * SEQ + qt * 128 + w * 32 + hf * 16 + m) * DIMM + h * 64);
#pragma unroll
        for (int i = 0; i < 4; ++i)
#pragma unroll
            for (int rp = 0; rp < 2; ++rp) {
                float o0 = oa[hf][i][2 * rp] * inv, o1 = oa[hf][i][2 * rp + 1] * inv;
                unsigned int pk;
                asm("v_cvt_pk_bf16_f32 %0, %1, %2" : "=v"(pk) : "v"(o0), "v"(o1));
                orow[i * 8 + g * 2 + rp] = pk;
            }
    }
}

// ---------------- launch ----------------
extern "C" void kernel_launch(void* const* d_in, const int* in_sizes, int n_in,
                              void* d_out, int out_size, void* d_ws, size_t ws_size,
                              hipStream_t stream) {
    const float* x     = (const float*)d_in[0];
    const float* g1    = (const float*)d_in[1];
    const float* b1    = (const float*)d_in[2];
    const float* W_qkv = (const float*)d_in[3];
    const float* g2    = (const float*)d_in[4];
    const float* b2    = (const float*)d_in[5];
    const float* W_out = (const float*)d_in[6];
    const float* b_out = (const float*)d_in[7];
    float* out = (float*)d_out;

    char* ws = (char*)d_ws;
    float* part   = (float*)(ws);                                // 320 floats
    __bf16* Wq1 = (__bf16*)(ws + 4096);                          // [1536,512]
    __bf16* Wq2 = (__bf16*)(ws + 1576960);                       // [512,512]
    __bf16* Xln = (__bf16*)(ws + 2101248);                       // [8192,512] (LN1 out; reused for LN2 out)
    __bf16* QKV = (__bf16*)(ws + 10489856);                      // [8192,1536]
    __bf16* AO  = (__bf16*)(ws + 35655680);                      // [8192,512]
    // total = 44,044,288 B (proven footprint)

    absum_all<<<320, 256, 0, stream>>>(W_qkv, W_out, part);
    quant_ln<<<3072, 256, 0, stream>>>(W_qkv, W_out, part, x, g1, b1, Wq1, Wq2, Xln);
    gemm_lds<TRIPLE, false, false><<<dim3(64, 12), 256, 0, stream>>>(Xln, Wq1, nullptr, QKV, nullptr);
    attn_mfma<<<dim3(64, 8), 256, 0, stream>>>(QKV, AO);
    ln_fast<__bf16><<<MROWS / 4, 256, 0, stream>>>(AO, g2, b2, Xln);
    gemm_lds<DIMM, true, true><<<dim3(64, 4), 256, 0, stream>>>(Xln, Wq2, b_out, nullptr, out);
}

// Round 22
// 85.151 us; speedup vs baseline: 1.1010x; 1.0025x over previous
//
#include <hip/hip_runtime.h>
#include <hip/hip_bf16.h>

typedef __bf16 bf16x8 __attribute__((ext_vector_type(8)));
typedef float  f32x4  __attribute__((ext_vector_type(4)));

#define SEQ   1024
#define BATCH 8
#define DIMM  512
#define HEADS 8
#define DHEAD 64
#define TRIPLE 1536
#define MROWS (BATCH*SEQ)   // 8192

#define GLOAD_LDS16(g, l) __builtin_amdgcn_global_load_lds( \
    (const __attribute__((address_space(1))) void*)(const void*)(g), \
    (__attribute__((address_space(3))) void*)(void*)(l), 16, 0, 0)

// ---------------- merged |w| partial sums ----------------
__global__ __launch_bounds__(256) void absum_all(const float* __restrict__ w1,
                                                 const float* __restrict__ w2,
                                                 float* __restrict__ part) {
    const int bid = blockIdx.x, tid = threadIdx.x;
    float s = 0.f;
    if (bid < 256) {
        const float4* p = (const float4*)w1;
        for (int i = bid * 256 + tid; i < 196608; i += 65536) {
            float4 v = p[i];
            s += fabsf(v.x) + fabsf(v.y) + fabsf(v.z) + fabsf(v.w);
        }
    } else {
        const float4* p = (const float4*)w2;
        for (int i = (bid - 256) * 256 + tid; i < 65536; i += 16384) {
            float4 v = p[i];
            s += fabsf(v.x) + fabsf(v.y) + fabsf(v.z) + fabsf(v.w);
        }
    }
    for (int o = 32; o; o >>= 1) s += __shfl_down(s, o);
    __shared__ float red[4];
    if (!(tid & 63)) red[tid >> 6] = s;
    __syncthreads();
    if (tid == 0) part[bid] = red[0] + red[1] + red[2] + red[3];
}

// ---------------- fused: ternary quantize (blocks 0..1023) || LN1 (blocks 1024..3071) ----------------
// (r18/r20-verified)
__global__ __launch_bounds__(256) void quant_ln(const float* __restrict__ w1,
                                                const float* __restrict__ w2,
                                                const float* __restrict__ part,
                                                const float* __restrict__ x,
                                                const float* __restrict__ g1,
                                                const float* __restrict__ b1,
                                                __bf16* __restrict__ o1,
                                                __bf16* __restrict__ o2,
                                                __bf16* __restrict__ y) {
    const int bid = blockIdx.x, tid = threadIdx.x;
    if (bid < 1024) {
        float acc = 0.f;
        if (bid < 768) acc = part[tid];
        else if (tid < 64) acc = part[256 + tid];
        for (int o = 32; o; o >>= 1) acc += __shfl_down(acc, o);
        __shared__ float red[4];
        if (!(tid & 63)) red[tid >> 6] = acc;
        __syncthreads();
        const float tot = red[0] + red[1] + red[2] + red[3];
        const float s = (bid < 768) ? tot / 786432.0f : tot / 262144.0f;
        const float inv = 1.f / (s + 1e-6f);
        const float* w; __bf16* o; int idx;
        if (bid < 768) { w = w1; o = o1; idx = (bid * 256 + tid) * 4; }
        else           { w = w2; o = o2; idx = ((bid - 768) * 256 + tid) * 4; }
        float4 v = *reinterpret_cast<const float4*>(w + idx);
        o[idx + 0] = (__bf16)(rintf(fminf(1.f, fmaxf(-1.f, v.x * inv))) * s);
        o[idx + 1] = (__bf16)(rintf(fminf(1.f, fmaxf(-1.f, v.y * inv))) * s);
        o[idx + 2] = (__bf16)(rintf(fminf(1.f, fmaxf(-1.f, v.z * inv))) * s);
        o[idx + 3] = (__bf16)(rintf(fminf(1.f, fmaxf(-1.f, v.w * inv))) * s);
    } else {
        const int row = (bid - 1024) * 4 + (tid >> 6);
        const int lane = tid & 63;
        const float4* xr = (const float4*)(x + (size_t)row * DIMM + lane * 8);
        float4 a = xr[0], bq = xr[1];
        float v[8] = {a.x, a.y, a.z, a.w, bq.x, bq.y, bq.z, bq.w};
        float s = 0.f, sq = 0.f;
#pragma unroll
        for (int e = 0; e < 8; ++e) { s += v[e]; sq += v[e] * v[e]; }
        for (int o = 32; o; o >>= 1) { s += __shfl_xor(s, o); sq += __shfl_xor(sq, o); }
        const float mu = s * (1.f / DIMM);
        const float invs = rsqrtf(sq * (1.f / DIMM) - mu * mu + 1e-5f);
        const float4* gp = (const float4*)(g1 + lane * 8);
        const float4* bp = (const float4*)(b1 + lane * 8);
        float4 g0 = gp[0], g1v = gp[1], b0 = bp[0], b1v = bp[1];
        float o_[8] = {
            (v[0] - mu) * invs * g0.x + b0.x, (v[1] - mu) * invs * g0.y + b0.y,
            (v[2] - mu) * invs * g0.z + b0.z, (v[3] - mu) * invs * g0.w + b0.w,
            (v[4] - mu) * invs * g1v.x + b1v.x, (v[5] - mu) * invs * g1v.y + b1v.y,
            (v[6] - mu) * invs * g1v.z + b1v.z, (v[7] - mu) * invs * g1v.w + b1v.w };
        uint4 st;
        asm("v_cvt_pk_bf16_f32 %0, %1, %2" : "=v"(st.x) : "v"(o_[0]), "v"(o_[1]));
        asm("v_cvt_pk_bf16_f32 %0, %1, %2" : "=v"(st.y) : "v"(o_[2]), "v"(o_[3]));
        asm("v_cvt_pk_bf16_f32 %0, %1, %2" : "=v"(st.z) : "v"(o_[4]), "v"(o_[5]));
        asm("v_cvt_pk_bf16_f32 %0, %1, %2" : "=v"(st.w) : "v"(o_[6]), "v"(o_[7]));
        *reinterpret_cast<uint4*>(y + (size_t)row * DIMM + lane * 8) = st;
    }
}

// ---------------- wave-per-row layernorm (row = 512), output bf16 ----------------
template<typename TIN>
__global__ __launch_bounds__(256) void ln_fast(const TIN* __restrict__ x,
                                               const float* __restrict__ g,
                                               const float* __restrict__ bta,
                                               __bf16* __restrict__ y) {
    const int row = blockIdx.x * 4 + (threadIdx.x >> 6);
    const int lane = threadIdx.x & 63;
    float v[8];
    if constexpr (sizeof(TIN) == 4) {
        const float4* xr = (const float4*)((const float*)x + (size_t)row * DIMM + lane * 8);
        float4 a = xr[0], bq = xr[1];
        v[0] = a.x; v[1] = a.y; v[2] = a.z; v[3] = a.w;
        v[4] = bq.x; v[5] = bq.y; v[6] = bq.z; v[7] = bq.w;
    } else {
        bf16x8 a = *reinterpret_cast<const bf16x8*>((const __bf16*)x + (size_t)row * DIMM + lane * 8);
#pragma unroll
        for (int e = 0; e < 8; ++e) v[e] = (float)a[e];
    }
    float s = 0.f, sq = 0.f;
#pragma unroll
    for (int e = 0; e < 8; ++e) { s += v[e]; sq += v[e] * v[e]; }
    for (int o = 32; o; o >>= 1) { s += __shfl_xor(s, o); sq += __shfl_xor(sq, o); }
    const float mu = s * (1.f / DIMM);
    const float invs = rsqrtf(sq * (1.f / DIMM) - mu * mu + 1e-5f);
    const float4* gp = (const float4*)(g + lane * 8);
    const float4* bp = (const float4*)(bta + lane * 8);
    float4 g0 = gp[0], g1 = gp[1], b0 = bp[0], b1 = bp[1];
    float o_[8] = {
        (v[0] - mu) * invs * g0.x + b0.x, (v[1] - mu) * invs * g0.y + b0.y,
        (v[2] - mu) * invs * g0.z + b0.z, (v[3] - mu) * invs * g0.w + b0.w,
        (v[4] - mu) * invs * g1.x + b1.x, (v[5] - mu) * invs * g1.y + b1.y,
        (v[6] - mu) * invs * g1.z + b1.z, (v[7] - mu) * invs * g1.w + b1.w };
    uint4 st;
    asm("v_cvt_pk_bf16_f32 %0, %1, %2" : "=v"(st.x) : "v"(o_[0]), "v"(o_[1]));
    asm("v_cvt_pk_bf16_f32 %0, %1, %2" : "=v"(st.y) : "v"(o_[2]), "v"(o_[3]));
    asm("v_cvt_pk_bf16_f32 %0, %1, %2" : "=v"(st.z) : "v"(o_[4]), "v"(o_[5]));
    asm("v_cvt_pk_bf16_f32 %0, %1, %2" : "=v"(st.w) : "v"(o_[6]), "v"(o_[7]));
    *reinterpret_cast<uint4*>(y + (size_t)row * DIMM + lane * 8) = st;
}

// ---------------- LDS-staged MFMA GEMM (round-6 exact) ----------------
template<int NCOLS, bool BIAS, bool OUT_F32>
__global__ __launch_bounds__(256) void gemm_lds(const __bf16* __restrict__ A,
                                                const __bf16* __restrict__ Wt,
                                                const float* __restrict__ bias,
                                                __bf16* __restrict__ outb,
                                                float* __restrict__ outf) {
    const int K = DIMM;
    __shared__ __align__(16) __bf16 As[2][4096];
    __shared__ __align__(16) __bf16 Bs[2][4096];

    const int tid = threadIdx.x;
    const int w = tid >> 6, lane = tid & 63;
    const int m = lane & 15, g = lane >> 4;
    const int mi = w >> 1, ni = w & 1;

    const int trow = tid >> 2;
    const int tc = tid & 3;
    const int sc = (tc ^ ((trow >> 1) & 3)) * 8;
    const __bf16* a0 = A  + (size_t)(blockIdx.x * 128 + trow) * K + sc;
    const __bf16* a1 = a0 + (size_t)64 * K;
    const __bf16* b0 = Wt + (size_t)(blockIdx.y * 128 + trow) * K + sc;
    const __bf16* b1 = b0 + (size_t)64 * K;

    f32x4 acc[4][4] = {};

    GLOAD_LDS16(a0, (char*)As[0] + tid * 16);
    GLOAD_LDS16(a1, (char*)As[0] + 4096 + tid * 16);
    GLOAD_LDS16(b0, (char*)Bs[0] + tid * 16);
    GLOAD_LDS16(b1, (char*)Bs[0] + 4096 + tid * 16);

    int cur = 0;
    for (int k0 = 0; k0 < K; k0 += 32) {
        __syncthreads();
        if (k0 + 32 < K) {
            GLOAD_LDS16(a0 + k0 + 32, (char*)As[cur ^ 1] + tid * 16);
            GLOAD_LDS16(a1 + k0 + 32, (char*)As[cur ^ 1] + 4096 + tid * 16);
            GLOAD_LDS16(b0 + k0 + 32, (char*)Bs[cur ^ 1] + tid * 16);
            GLOAD_LDS16(b1 + k0 + 32, (char*)Bs[cur ^ 1] + 4096 + tid * 16);
        }

        const char* Ab = (const char*)As[cur];
        const char* Bb = (const char*)Bs[cur];
        bf16x8 af[4], bfr[4];
#pragma unroll
        for (int i = 0; i < 4; ++i) {
            const int ra = mi * 64 + i * 16 + m;
            af[i] = *reinterpret_cast<const bf16x8*>(Ab + ra * 64 + ((g ^ ((ra >> 1) & 3)) << 4));
        }
#pragma unroll
        for (int j = 0; j < 4; ++j) {
            const int rb = ni * 64 + j * 16 + m;
            bfr[j] = *reinterpret_cast<const bf16x8*>(Bb + rb * 64 + ((g ^ ((rb >> 1) & 3)) << 4));
        }
#pragma unroll
        for (int i = 0; i < 4; ++i)
#pragma unroll
            for (int j = 0; j < 4; ++j)
                acc[i][j] = __builtin_amdgcn_mfma_f32_16x16x32_bf16(af[i], bfr[j], acc[i][j], 0, 0, 0);
        cur ^= 1;
    }

    const int orow0 = blockIdx.x * 128 + mi * 64 + g * 4;
    const int ocol0 = blockIdx.y * 128 + ni * 64;
#pragma unroll
    for (int i = 0; i < 4; ++i)
#pragma unroll
        for (int j = 0; j < 4; ++j)
#pragma unroll
            for (int r = 0; r < 4; ++r) {
                int row = orow0 + i * 16 + r;
                int col = ocol0 + j * 16 + m;
                float v = acc[i][j][r];
                if (BIAS) v += bias[col];
                if (OUT_F32) outf[(size_t)row * NCOLS + col] = v;
                else         outb[(size_t)row * NCOLS + col] = (__bf16)v;
            }
}

// ---------------- MFMA flash attention (r12/r20-verified body, NO setprio) ----------------
// grid (64 bh, 8 qt); 256 threads = 4 waves, 32 q-rows/wave (two 16-row halves).
// lin%8 == h -> same-XCD K/V sharing. Reg-staged K/V with both-side swizzles,
// 2 barriers/tile, t+1 reg prefetch. NOTE: s_setprio around these MFMA clusters
// corrupted results twice (r9, r19) on this toolchain -- do not re-add. Split-KV
// variant NaN'd (r21) -- root cause undiagnosed headlessly; do not re-roll blind.
__global__ __launch_bounds__(256, 2) void attn_mfma(const __bf16* __restrict__ qkv,
                                                    __bf16* __restrict__ out) {
    const int qt = blockIdx.y, bh = blockIdx.x;
    const int b = bh >> 3, h = bh & 7;
    const int tid = threadIdx.x;
    const int w = tid >> 6, lane = tid & 63;
    const int g = lane >> 4, m = lane & 15;

    __shared__ __align__(16) __bf16 Kb[4096];      // [64 key][64 d], chunk c at c^(key&7)
    __shared__ __align__(16) __bf16 Vt[4096];      // [64 d][64 key], chunk c at c^((d>>3)^(d&7))
    __shared__ __align__(16) __bf16 Pl[4][2048];   // per-wave [32 q][64 key], chunk c at c^(q&7)

    bf16x8 qf[2][2];
    {
        const __bf16* qp = qkv + (size_t)(b * SEQ + qt * 128 + w * 32 + m) * TRIPLE + h * 64 + g * 8;
#pragma unroll
        for (int hf = 0; hf < 2; ++hf) {
            qf[hf][0] = *reinterpret_cast<const bf16x8*>(qp + (size_t)hf * 16 * TRIPLE);
            qf[hf][1] = *reinterpret_cast<const bf16x8*>(qp + (size_t)hf * 16 * TRIPLE + 32);
#pragma unroll
            for (int e = 0; e < 8; ++e) {
                qf[hf][0][e] = (__bf16)((float)qf[hf][0][e] * 0.125f);
                qf[hf][1][e] = (__bf16)((float)qf[hf][1][e] * 0.125f);
            }
        }
    }

    const int srow = tid >> 3;          // 0..31
    const int sc   = tid & 7;           // 0..7
    const size_t rbase = (size_t)(b * SEQ + srow) * TRIPLE + h * 64 + sc * 8;
    const __bf16* k0s = qkv + rbase + DIMM;
    const __bf16* v0s = qkv + rbase + 2 * DIMM;
    const __bf16* k1s = k0s + (size_t)32 * TRIPLE;
    const __bf16* v1s = v0s + (size_t)32 * TRIPLE;
    const int kstep = 64 * TRIPLE;

    char* kw0 = (char*)Kb + srow * 128 + ((sc ^ (srow & 7)) << 4);
    char* kw1 = kw0 + 32 * 128;
    char* vbp = (char*)Vt;

    f32x4 oa[2][4] = {};
    float mrun[2] = {-1e30f, -1e30f}, lrun[2] = {0.f, 0.f};

    uint4 k0c = *reinterpret_cast<const uint4*>(k0s);
    uint4 k1c = *reinterpret_cast<const uint4*>(k1s);
    uint4 v0c = *reinterpret_cast<const uint4*>(v0s);
    uint4 v1c = *reinterpret_cast<const uint4*>(v1s);
    uint4 k0n = {}, k1n = {}, v0n = {}, v1n = {};

    for (int t = 0; t < 16; ++t) {
        __syncthreads();

        *reinterpret_cast<bf16x8*>(kw0) = *reinterpret_cast<bf16x8*>(&k0c);
        *reinterpret_cast<bf16x8*>(kw1) = *reinterpret_cast<bf16x8*>(&k1c);
        {
            bf16x8 va = *reinterpret_cast<bf16x8*>(&v0c);
            bf16x8 vb = *reinterpret_cast<bf16x8*>(&v1c);
#pragma unroll
            for (int e = 0; e < 8; ++e) {
                const int dro = (sc * 8 + e) * 128;
                const int sw = ((sc ^ e) & 7) << 4;
                *(__bf16*)(vbp + dro + ((srow * 2) ^ sw))        = va[e];
                *(__bf16*)(vbp + dro + (((srow + 32) * 2) ^ sw)) = vb[e];
            }
        }
        __syncthreads();

        if (t < 15) {
            k0n = *reinterpret_cast<const uint4*>(k0s + (size_t)(t + 1) * kstep);
            k1n = *reinterpret_cast<const uint4*>(k1s + (size_t)(t + 1) * kstep);
            v0n = *reinterpret_cast<const uint4*>(v0s + (size_t)(t + 1) * kstep);
            v1n = *reinterpret_cast<const uint4*>(v1s + (size_t)(t + 1) * kstep);
        }

        // ---- S^T = K @ Q^T ----
        const char* kb = (const char*)Kb;
        f32x4 sa[2][4];
#pragma unroll
        for (int hf = 0; hf < 2; ++hf)
#pragma unroll
            for (int i = 0; i < 4; ++i) sa[hf][i] = (f32x4){0.f, 0.f, 0.f, 0.f};
#pragma unroll
        for (int kc = 0; kc < 2; ++kc) {
            const int cp = ((kc * 4 + g) ^ (m & 7)) << 4;
#pragma unroll
            for (int i = 0; i < 4; ++i) {
                bf16x8 kf = *reinterpret_cast<const bf16x8*>(kb + (i * 16 + m) * 128 + cp);
                sa[0][i] = __builtin_amdgcn_mfma_f32_16x16x32_bf16(kf, qf[0][kc], sa[0][i], 0, 0, 0);
                sa[1][i] = __builtin_amdgcn_mfma_f32_16x16x32_bf16(kf, qf[1][kc], sa[1][i], 0, 0, 0);
            }
        }

        // ---- online softmax per half + P pack/store ----
        char* pw = (char*)Pl[w] + m * 128;
        const int psw = (m & 7) << 4;
#pragma unroll
        for (int hf = 0; hf < 2; ++hf) {
            float mx = -1e30f;
#pragma unroll
            for (int i = 0; i < 4; ++i)
#pragma unroll
                for (int r = 0; r < 4; ++r) mx = fmaxf(mx, sa[hf][i][r]);
            mx = fmaxf(mx, __shfl_xor(mx, 16));
            mx = fmaxf(mx, __shfl_xor(mx, 32));
            const float mnew = fmaxf(mrun[hf], mx);
            float p[4][4];
            float ps = 0.f;
#pragma unroll
            for (int i = 0; i < 4; ++i)
#pragma unroll
                for (int r = 0; r < 4; ++r) { p[i][r] = __expf(sa[hf][i][r] - mnew); ps += p[i][r]; }
            ps += __shfl_xor(ps, 16);
            ps += __shfl_xor(ps, 32);
            const float al = __expf(mrun[hf] - mnew);
            mrun[hf] = mnew;
            lrun[hf] = lrun[hf] * al + ps;
#pragma unroll
            for (int i = 0; i < 4; ++i)
#pragma unroll
                for (int r = 0; r < 4; ++r) oa[hf][i][r] *= al;
#pragma unroll
            for (int i = 0; i < 4; ++i) {
                uint2 pk;
                asm("v_cvt_pk_bf16_f32 %0, %1, %2" : "=v"(pk.x) : "v"(p[i][0]), "v"(p[i][1]));
                asm("v_cvt_pk_bf16_f32 %0, %1, %2" : "=v"(pk.y) : "v"(p[i][2]), "v"(p[i][3]));
                *reinterpret_cast<uint2*>(pw + hf * 16 * 128 + ((i * 32 + g * 8) ^ psw)) = pk;
            }
        }

        // ---- P fragments ----
        bf16x8 pf[2][2];
#pragma unroll
        for (int hf = 0; hf < 2; ++hf)
#pragma unroll
            for (int kc = 0; kc < 2; ++kc)
                pf[hf][kc] = *reinterpret_cast<const bf16x8*>(
                    pw + hf * 16 * 128 + ((kc * 64 + g * 16) ^ psw));

        // ---- O^T += V^T @ P^T ----
#pragma unroll
        for (int kc = 0; kc < 2; ++kc)
#pragma unroll
            for (int i = 0; i < 4; ++i) {
                const int sv = ((i * 2 + (m >> 3)) ^ (m & 7)) & 7;
                bf16x8 vf = *reinterpret_cast<const bf16x8*>(
                    vbp + (i * 16 + m) * 128 + (((kc * 4 + g) ^ sv) << 4));
                oa[0][i] = __builtin_amdgcn_mfma_f32_16x16x32_bf16(vf, pf[0][kc], oa[0][i], 0, 0, 0);
                oa[1][i] = __builtin_amdgcn_mfma_f32_16x16x32_bf16(vf, pf[1][kc], oa[1][i], 0, 0, 0);
            }

        k0c = k0n; k1c = k1n; v0c = v0n; v1c = v1n;
    }

#pragma unroll
    for (int hf = 0; hf < 2; ++hf) {
        const float inv = 1.0f / lrun[hf];
        unsigned int* orow = (unsigned int*)(out +
            (size_t)(b * SEQ + qt * 128 + w * 32 + hf * 16 + m) * DIMM + h * 64);
#pragma unroll
        for (int i = 0; i < 4; ++i)
#pragma unroll
            for (int rp = 0; rp < 2; ++rp) {
                float o0 = oa[hf][i][2 * rp] * inv, o1 = oa[hf][i][2 * rp + 1] * inv;
                unsigned int pk;
                asm("v_cvt_pk_bf16_f32 %0, %1, %2" : "=v"(pk) : "v"(o0), "v"(o1));
                orow[i * 8 + g * 2 + rp] = pk;
            }
    }
}

// ---------------- launch ----------------
extern "C" void kernel_launch(void* const* d_in, const int* in_sizes, int n_in,
                              void* d_out, int out_size, void* d_ws, size_t ws_size,
                              hipStream_t stream) {
    const float* x     = (const float*)d_in[0];
    const float* g1    = (const float*)d_in[1];
    const float* b1    = (const float*)d_in[2];
    const float* W_qkv = (const float*)d_in[3];
    const float* g2    = (const float*)d_in[4];
    const float* b2    = (const float*)d_in[5];
    const float* W_out = (const float*)d_in[6];
    const float* b_out = (const float*)d_in[7];
    float* out = (float*)d_out;

    char* ws = (char*)d_ws;
    float* part   = (float*)(ws);                                // 320 floats
    __bf16* Wq1 = (__bf16*)(ws + 4096);                          // [1536,512]
    __bf16* Wq2 = (__bf16*)(ws + 1576960);                       // [512,512]
    __bf16* Xln = (__bf16*)(ws + 2101248);                       // [8192,512] (LN1 out; reused for LN2 out)
    __bf16* QKV = (__bf16*)(ws + 10489856);                      // [8192,1536]
    __bf16* AO  = (__bf16*)(ws + 35655680);                      // [8192,512]
    // total = 44,044,288 B (proven footprint)

    absum_all<<<320, 256, 0, stream>>>(W_qkv, W_out, part);
    quant_ln<<<3072, 256, 0, stream>>>(W_qkv, W_out, part, x, g1, b1, Wq1, Wq2, Xln);
    gemm_lds<TRIPLE, false, false><<<dim3(64, 12), 256, 0, stream>>>(Xln, Wq1, nullptr, QKV, nullptr);
    attn_mfma<<<dim3(64, 8), 256, 0, stream>>>(QKV, AO);
    ln_fast<__bf16><<<MROWS / 4, 256, 0, stream>>>(AO, g2, b2, Xln);
    gemm_lds<DIMM, true, true><<<dim3(64, 4), 256, 0, stream>>>(Xln, Wq2, b_out, nullptr, out);
}